// Round 3
// baseline (56.078 us; speedup 1.0000x reference)
//
#include <hip/hip_runtime.h>
#include <stdint.h>

// QuantConv1D (binary, K=3, Cin=128, Cout=256, VALID) + bias + BN(inference)
// via XNOR-popcount on bit-packed signs.
//
// out(b,t,co) = p*A[co] + C[co], p = popc over 384 xor'd bits,
// A = -2/sqrt(var+eps), C = (384+bias-mean)/sqrt(var+eps) + beta.
//
// R2: widened memory ops 4x.
//  - pack phase: one float4 load per lane = 2 rows/instr; bit order within a
//    row is permuted (word i holds cin == i mod 4) and pack_w applies the SAME
//    permutation to kernel bits (popcount is permutation-invariant).
//  - conv: 4 cout per thread, float4 stores (1 KB/wave), 1/4 the LDS reads.

#define B 64
#define T 2048
#define CIN 128
#define COUT 256
#define KW 3
#define TOUT (T - KW + 1)        // 2046
#define TCHUNK 66                // 2046 = 31 * 66
#define CHUNKS 31
#define NROWS (TCHUNK + KW - 1)  // 68 x-rows per block

__device__ __forceinline__ int popc_row(uint4 r, uint4 k) {
    return __popc(r.x ^ k.x) + __popc(r.y ^ k.y) +
           __popc(r.z ^ k.z) + __popc(r.w ^ k.w);
}

// ---- pass 1: pack kernel signs (permuted: word i bit b <-> cin = 4b+i) ----
// kb32[(k*4+i)*COUT + co]; grid = 12 blocks (k*4+i).
__global__ __launch_bounds__(256) void pack_w_kernel(const float* __restrict__ ker,
                                                     const float* __restrict__ bias,
                                                     const float* __restrict__ beta,
                                                     const float* __restrict__ mean,
                                                     const float* __restrict__ var,
                                                     uint32_t* __restrict__ kb32,
                                                     float* __restrict__ A,
                                                     float* __restrict__ C) {
    int k  = blockIdx.x >> 2;       // 0..2
    int i  = blockIdx.x & 3;        // word index 0..3
    int co = threadIdx.x;           // 0..255
    const float* src = ker + ((size_t)(k * CIN + i)) * COUT + co;
    uint32_t wbits = 0;
    #pragma unroll 8
    for (int bb = 0; bb < 32; ++bb) {
        if (src[(size_t)(4 * bb) * COUT] >= 0.0f) wbits |= (1u << bb);
    }
    kb32[(size_t)(k * 4 + i) * COUT + co] = wbits;
    if (blockIdx.x == 0) {
        float inv = 1.0f / sqrtf(var[co] + 1e-3f);
        A[co] = -2.0f * inv;
        C[co] = (384.0f + bias[co] - mean[co]) * inv + beta[co];
    }
}

// ---- pass 2: fused pack-x + popcount conv + affine ------------------------
__global__ __launch_bounds__(256) void conv_fused_kernel(const float* __restrict__ x,
                                                         const uint32_t* __restrict__ kb32,
                                                         const float* __restrict__ A,
                                                         const float* __restrict__ C,
                                                         float* __restrict__ out) {
    const int tid = threadIdx.x;
    const int wv  = tid >> 6;       // wave 0..3
    const int l   = tid & 63;       // lane
    const int chunk = blockIdx.x;
    const int b     = chunk / CHUNKS;
    const int t0    = (chunk % CHUNKS) * TCHUNK;

    __shared__ uint4 xs[NROWS];     // per-row 128 sign bits, permuted format

    // --- pack: each wave-round loads 1024B = 2 rows via float4 ---
    const float* xbase = x + ((size_t)b * T + t0) * CIN;
    for (int rd = wv; rd < NROWS / 2; rd += 4) {
        float4 v = *(const float4*)(xbase + (size_t)rd * 256 + l * 4);
        // ballot i: bit l = sign(row r0+(l>=32), cin=(l&31)*4+i)
        uint64_t m0 = __ballot(v.x >= 0.0f);
        uint64_t m1 = __ballot(v.y >= 0.0f);
        uint64_t m2 = __ballot(v.z >= 0.0f);
        uint64_t m3 = __ballot(v.w >= 0.0f);
        if (l == 0) {
            xs[rd * 2] = make_uint4((uint32_t)m0, (uint32_t)m1,
                                    (uint32_t)m2, (uint32_t)m3);
        } else if (l == 1) {
            xs[rd * 2 + 1] = make_uint4((uint32_t)(m0 >> 32), (uint32_t)(m1 >> 32),
                                        (uint32_t)(m2 >> 32), (uint32_t)(m3 >> 32));
        }
    }

    // --- kernel bits for this thread's 4 cout (vector loads + reg transpose) ---
    const int co0 = l * 4;
    uint4 kw_raw[KW][4];
    #pragma unroll
    for (int k = 0; k < KW; ++k)
        #pragma unroll
        for (int i = 0; i < 4; ++i)
            kw_raw[k][i] = *(const uint4*)(kb32 + (size_t)(k * 4 + i) * COUT + co0);
    // kj[j][k] = the 4 words for cout co0+j, tap k  (compile-time transpose)
    uint4 kj[4][KW];
    #pragma unroll
    for (int j = 0; j < 4; ++j)
        #pragma unroll
        for (int k = 0; k < KW; ++k)
            kj[j][k] = make_uint4(((const uint32_t*)&kw_raw[k][0])[j],
                                  ((const uint32_t*)&kw_raw[k][1])[j],
                                  ((const uint32_t*)&kw_raw[k][2])[j],
                                  ((const uint32_t*)&kw_raw[k][3])[j]);
    const float4 av = *(const float4*)(A + co0);
    const float4 cv = *(const float4*)(C + co0);

    __syncthreads();

    // --- wave-private t ranges: {18,16,16,16} starting {0,18,34,50} ---
    const int tstart = (wv == 0) ? 0 : 18 + (wv - 1) * 16;
    const int tlen   = (wv == 0) ? 18 : 16;

    float* orow = out + ((size_t)b * TOUT + t0 + tstart) * COUT + co0;
    uint4 r0 = xs[tstart];
    uint4 r1 = xs[tstart + 1];
    #pragma unroll 2
    for (int tt = 0; tt < tlen; tt += 2) {
        uint4 r2 = xs[tstart + tt + 2];
        uint4 r3 = xs[tstart + tt + 3];
        float4 o0, o1;
        int p;
        p = popc_row(r0, kj[0][0]) + popc_row(r1, kj[0][1]) + popc_row(r2, kj[0][2]);
        o0.x = fmaf((float)p, av.x, cv.x);
        p = popc_row(r1, kj[0][0]) + popc_row(r2, kj[0][1]) + popc_row(r3, kj[0][2]);
        o1.x = fmaf((float)p, av.x, cv.x);
        p = popc_row(r0, kj[1][0]) + popc_row(r1, kj[1][1]) + popc_row(r2, kj[1][2]);
        o0.y = fmaf((float)p, av.y, cv.y);
        p = popc_row(r1, kj[1][0]) + popc_row(r2, kj[1][1]) + popc_row(r3, kj[1][2]);
        o1.y = fmaf((float)p, av.y, cv.y);
        p = popc_row(r0, kj[2][0]) + popc_row(r1, kj[2][1]) + popc_row(r2, kj[2][2]);
        o0.z = fmaf((float)p, av.z, cv.z);
        p = popc_row(r1, kj[2][0]) + popc_row(r2, kj[2][1]) + popc_row(r3, kj[2][2]);
        o1.z = fmaf((float)p, av.z, cv.z);
        p = popc_row(r0, kj[3][0]) + popc_row(r1, kj[3][1]) + popc_row(r2, kj[3][2]);
        o0.w = fmaf((float)p, av.w, cv.w);
        p = popc_row(r1, kj[3][0]) + popc_row(r2, kj[3][1]) + popc_row(r3, kj[3][2]);
        o1.w = fmaf((float)p, av.w, cv.w);

        *(float4*)(orow + (size_t)tt * COUT)       = o0;
        *(float4*)(orow + (size_t)(tt + 1) * COUT) = o1;
        r0 = r2;
        r1 = r3;
    }
}

extern "C" void kernel_launch(void* const* d_in, const int* in_sizes, int n_in,
                              void* d_out, int out_size, void* d_ws, size_t ws_size,
                              hipStream_t stream) {
    const float* x    = (const float*)d_in[0];
    const float* ker  = (const float*)d_in[1];
    const float* bias = (const float*)d_in[2];
    const float* beta = (const float*)d_in[3];
    const float* mean = (const float*)d_in[4];
    const float* var  = (const float*)d_in[5];
    float* out = (float*)d_out;

    // workspace: kb32 (12 KB) | A (1 KB) | C (1 KB)
    uint32_t* kb32 = (uint32_t*)d_ws;
    float*    A    = (float*)(kb32 + (size_t)KW * 4 * COUT);
    float*    C    = A + COUT;

    pack_w_kernel<<<KW * 4, 256, 0, stream>>>(ker, bias, beta, mean, var, kb32, A, C);
    conv_fused_kernel<<<B * CHUNKS, 256, 0, stream>>>(x, kb32, A, C, out);
}

// Round 4
// 44.817 us; speedup vs baseline: 1.2513x; 1.2513x over previous
//
#include <hip/hip_runtime.h>
#include <stdint.h>

// QuantConv1D (binary, K=3, Cin=128, Cout=256, VALID) + bias + BN(inference)
// via XNOR-popcount on bit-packed signs.
//
// out(b,t,co) = p*A[co] + C[co], p = popc over 384 xor'd bits,
// A = -2/sqrt(var+eps), C = (384+bias-mean)/sqrt(var+eps) + beta.
//
// R3: wave-autonomous streaming. No LDS, no __syncthreads.
//  - One float4 load/lane = 2 rows (1024B); 4 __ballot's ARE the packed rows,
//    wave-uniform in SGPRs (v_xor_b32 reads them as src0 directly).
//  - Each wave owns a 32-output window: load->ballot->popc->store stream
//    with 1-pair sliding register window and one prefetched load.
//  - Kernel bits pre-transposed co-major (kbT) so threads load their 12
//    uint4 fragments directly; no in-register transpose.

#define B 64
#define T 2048
#define CIN 128
#define COUT 256
#define KW 3
#define TOUT (T - KW + 1)   // 2046
#define TW 32               // outputs per wave-window
#define NWIN 64             // windows per batch row; last one overlaps (t0=2014)
#define WPB 4               // waves per block

// ---- pass 1: pack kernel signs, transposed layout ----
// kbT[co*12 + k*4 + i], word i bit b <-> cin = 4b+i  (matches ballot order)
__global__ __launch_bounds__(256) void pack_w_kernel(const float* __restrict__ ker,
                                                     const float* __restrict__ bias,
                                                     const float* __restrict__ beta,
                                                     const float* __restrict__ mean,
                                                     const float* __restrict__ var,
                                                     uint32_t* __restrict__ kbT,
                                                     float* __restrict__ A,
                                                     float* __restrict__ C) {
    int k  = blockIdx.x >> 2;       // 0..2
    int i  = blockIdx.x & 3;        // word index 0..3
    int co = threadIdx.x;           // 0..255
    const float* src = ker + ((size_t)(k * CIN + i)) * COUT + co;
    uint32_t wbits = 0;
    #pragma unroll 8
    for (int bb = 0; bb < 32; ++bb) {
        if (src[(size_t)(4 * bb) * COUT] >= 0.0f) wbits |= (1u << bb);
    }
    kbT[(size_t)co * 12 + k * 4 + i] = wbits;
    if (blockIdx.x == 0) {
        float inv = 1.0f / sqrtf(var[co] + 1e-3f);
        A[co] = -2.0f * inv;
        C[co] = (384.0f + bias[co] - mean[co]) * inv + beta[co];
    }
}

__device__ __forceinline__ int popc4(uint32_t a0, uint32_t a1, uint32_t a2,
                                     uint32_t a3, uint4 k) {
    return __popc(a0 ^ k.x) + __popc(a1 ^ k.y) + __popc(a2 ^ k.z) + __popc(a3 ^ k.w);
}

// ---- pass 2: wave-autonomous fused pack-x + popcount conv + affine ----
__global__ __launch_bounds__(256) void conv_kernel(const float* __restrict__ x,
                                                   const uint32_t* __restrict__ kbT,
                                                   const float* __restrict__ A,
                                                   const float* __restrict__ C,
                                                   float* __restrict__ out) {
    const int l   = threadIdx.x & 63;
    const int wv  = threadIdx.x >> 6;
    const int gw  = blockIdx.x * WPB + wv;          // 0..B*NWIN-1
    const int b   = gw >> 6;                        // /NWIN
    const int win = gw & (NWIN - 1);
    const int t0  = (win < NWIN - 1) ? win * TW : (TOUT - TW);  // last overlaps

    // per-thread kernel bits: kj[j][k] = 4 words for cout co0+j, tap k
    const int co0 = l * 4;
    uint4 kj[4][KW];
    #pragma unroll
    for (int j = 0; j < 4; ++j)
        #pragma unroll
        for (int k = 0; k < KW; ++k)
            kj[j][k] = *(const uint4*)(kbT + (size_t)(co0 + j) * 12 + k * 4);
    const float4 av = *(const float4*)(A + co0);
    const float4 cv = *(const float4*)(C + co0);

    // streaming source: lane l covers row (l>=32) of each pair, cins (l%32)*4..+3
    const float* xp = x + ((size_t)b * T + t0) * CIN + l * 4;

    float4 v = *(const float4*)xp; xp += 2 * CIN;   // pair 0 (rows 0,1)
    uint64_t p0 = __ballot(v.x >= 0.0f);
    uint64_t p1 = __ballot(v.y >= 0.0f);
    uint64_t p2 = __ballot(v.z >= 0.0f);
    uint64_t p3 = __ballot(v.w >= 0.0f);
    v = *(const float4*)xp; xp += 2 * CIN;          // pair 1 (rows 2,3)

    float* orow = out + ((size_t)b * TOUT + t0) * COUT + co0;

    #pragma unroll 2
    for (int j = 0; j < TW / 2; ++j) {
        float4 vn = v;
        if (j < TW / 2 - 1) vn = *(const float4*)xp; // prefetch pair j+2
        xp += 2 * CIN;

        uint64_t m0 = __ballot(v.x >= 0.0f);         // pair j+1: rows 2j+2, 2j+3
        uint64_t m1 = __ballot(v.y >= 0.0f);
        uint64_t m2 = __ballot(v.z >= 0.0f);
        uint64_t m3 = __ballot(v.w >= 0.0f);

        // row words (word c: bit b <-> cin 4b+c)
        uint32_t r0a = (uint32_t)p0,         r0b = (uint32_t)p1,         r0c = (uint32_t)p2,         r0d = (uint32_t)p3;
        uint32_t r1a = (uint32_t)(p0 >> 32), r1b = (uint32_t)(p1 >> 32), r1c = (uint32_t)(p2 >> 32), r1d = (uint32_t)(p3 >> 32);
        uint32_t r2a = (uint32_t)m0,         r2b = (uint32_t)m1,         r2c = (uint32_t)m2,         r2d = (uint32_t)m3;
        uint32_t r3a = (uint32_t)(m0 >> 32), r3b = (uint32_t)(m1 >> 32), r3c = (uint32_t)(m2 >> 32), r3d = (uint32_t)(m3 >> 32);

        float4 o0, o1;
        int p;
        // out t=2j: rows 2j,2j+1,2j+2 ; out t+1: rows 2j+1,2j+2,2j+3
        p = popc4(r0a,r0b,r0c,r0d, kj[0][0]) + popc4(r1a,r1b,r1c,r1d, kj[0][1]) + popc4(r2a,r2b,r2c,r2d, kj[0][2]);
        o0.x = fmaf((float)p, av.x, cv.x);
        p = popc4(r1a,r1b,r1c,r1d, kj[0][0]) + popc4(r2a,r2b,r2c,r2d, kj[0][1]) + popc4(r3a,r3b,r3c,r3d, kj[0][2]);
        o1.x = fmaf((float)p, av.x, cv.x);
        p = popc4(r0a,r0b,r0c,r0d, kj[1][0]) + popc4(r1a,r1b,r1c,r1d, kj[1][1]) + popc4(r2a,r2b,r2c,r2d, kj[1][2]);
        o0.y = fmaf((float)p, av.y, cv.y);
        p = popc4(r1a,r1b,r1c,r1d, kj[1][0]) + popc4(r2a,r2b,r2c,r2d, kj[1][1]) + popc4(r3a,r3b,r3c,r3d, kj[1][2]);
        o1.y = fmaf((float)p, av.y, cv.y);
        p = popc4(r0a,r0b,r0c,r0d, kj[2][0]) + popc4(r1a,r1b,r1c,r1d, kj[2][1]) + popc4(r2a,r2b,r2c,r2d, kj[2][2]);
        o0.z = fmaf((float)p, av.z, cv.z);
        p = popc4(r1a,r1b,r1c,r1d, kj[2][0]) + popc4(r2a,r2b,r2c,r2d, kj[2][1]) + popc4(r3a,r3b,r3c,r3d, kj[2][2]);
        o1.z = fmaf((float)p, av.z, cv.z);
        p = popc4(r0a,r0b,r0c,r0d, kj[3][0]) + popc4(r1a,r1b,r1c,r1d, kj[3][1]) + popc4(r2a,r2b,r2c,r2d, kj[3][2]);
        o0.w = fmaf((float)p, av.w, cv.w);
        p = popc4(r1a,r1b,r1c,r1d, kj[3][0]) + popc4(r2a,r2b,r2c,r2d, kj[3][1]) + popc4(r3a,r3b,r3c,r3d, kj[3][2]);
        o1.w = fmaf((float)p, av.w, cv.w);

        *(float4*)(orow + (size_t)(2 * j) * COUT)     = o0;
        *(float4*)(orow + (size_t)(2 * j + 1) * COUT) = o1;

        p0 = m0; p1 = m1; p2 = m2; p3 = m3;
        v = vn;
    }
}

extern "C" void kernel_launch(void* const* d_in, const int* in_sizes, int n_in,
                              void* d_out, int out_size, void* d_ws, size_t ws_size,
                              hipStream_t stream) {
    const float* x    = (const float*)d_in[0];
    const float* ker  = (const float*)d_in[1];
    const float* bias = (const float*)d_in[2];
    const float* beta = (const float*)d_in[3];
    const float* mean = (const float*)d_in[4];
    const float* var  = (const float*)d_in[5];
    float* out = (float*)d_out;

    // workspace: kbT (12 KB) | A (1 KB) | C (1 KB)
    uint32_t* kbT = (uint32_t*)d_ws;
    float*    A   = (float*)(kbT + (size_t)COUT * 12);
    float*    C   = A + COUT;

    pack_w_kernel<<<KW * 4, 256, 0, stream>>>(ker, bias, beta, mean, var, kbT, A, C);
    conv_kernel<<<(B * NWIN) / WPB, 256, 0, stream>>>(x, kbT, A, C, out);
}

// Round 6
// 43.616 us; speedup vs baseline: 1.2857x; 1.0275x over previous
//
#include <hip/hip_runtime.h>
#include <stdint.h>

// QuantConv1D (binary, K=3, Cin=128, Cout=256, VALID) + bias + BN(inference)
// via XNOR-popcount on bit-packed signs.
//
// out(b,t,co) = p*A[co] + C[co], p = popc over 384 xor'd bits,
// A = -2/sqrt(var+eps), C = (384+bias-mean)/sqrt(var+eps) + beta.
//
// R4: wave-autonomous streaming (no LDS/barriers), float4 load = 2 rows,
//     ballot masks ARE the packed rows (wave-uniform, SGPRs).
// R5: 4-output bodies with 2-deep load prefetch (2 float4 in flight),
//     nontemporal stores via ext_vector_type (out never re-read; keep L3
//     for x), tail prefetches address-clamped to row T-2.

#define B 64
#define T 2048
#define CIN 128
#define COUT 256
#define KW 3
#define TOUT (T - KW + 1)   // 2046
#define TW 32               // outputs per wave-window
#define NWIN 64             // windows per batch row; last overlaps (t0=2014)
#define WPB 4               // waves per block

typedef float f32x4 __attribute__((ext_vector_type(4)));

// ---- pass 1: pack kernel signs, transposed layout ----
// kbT[co*12 + k*4 + i], word i bit b <-> cin = 4b+i  (matches ballot order)
__global__ __launch_bounds__(256) void pack_w_kernel(const float* __restrict__ ker,
                                                     const float* __restrict__ bias,
                                                     const float* __restrict__ beta,
                                                     const float* __restrict__ mean,
                                                     const float* __restrict__ var,
                                                     uint32_t* __restrict__ kbT,
                                                     float* __restrict__ A,
                                                     float* __restrict__ C) {
    int k  = blockIdx.x >> 2;       // 0..2
    int i  = blockIdx.x & 3;        // word index 0..3
    int co = threadIdx.x;           // 0..255
    const float* src = ker + ((size_t)(k * CIN + i)) * COUT + co;
    uint32_t wbits = 0;
    #pragma unroll 8
    for (int bb = 0; bb < 32; ++bb) {
        if (src[(size_t)(4 * bb) * COUT] >= 0.0f) wbits |= (1u << bb);
    }
    kbT[(size_t)co * 12 + k * 4 + i] = wbits;
    if (blockIdx.x == 0) {
        float inv = 1.0f / sqrtf(var[co] + 1e-3f);
        A[co] = -2.0f * inv;
        C[co] = (384.0f + bias[co] - mean[co]) * inv + beta[co];
    }
}

__device__ __forceinline__ int popc4(uint4 r, uint4 k) {
    return __popc(r.x ^ k.x) + __popc(r.y ^ k.y) + __popc(r.z ^ k.z) + __popc(r.w ^ k.w);
}

// ---- pass 2: wave-autonomous fused pack-x + popcount conv + affine ----
__global__ __launch_bounds__(256) void conv_kernel(const float* __restrict__ x,
                                                   const uint32_t* __restrict__ kbT,
                                                   const float* __restrict__ A,
                                                   const float* __restrict__ C,
                                                   float* __restrict__ out) {
    const int l   = threadIdx.x & 63;
    const int wv  = threadIdx.x >> 6;
    const int gw  = blockIdx.x * WPB + wv;          // 0..B*NWIN-1
    const int b   = gw >> 6;                        // /NWIN
    const int win = gw & (NWIN - 1);
    const int t0  = (win < NWIN - 1) ? win * TW : (TOUT - TW);  // last overlaps

    // per-thread kernel bits: kj[j][k] = 4 words for cout co0+j, tap k
    const int co0 = l * 4;
    uint4 kj[4][KW];
    #pragma unroll
    for (int j = 0; j < 4; ++j)
        #pragma unroll
        for (int k = 0; k < KW; ++k)
            kj[j][k] = *(const uint4*)(kbT + (size_t)(co0 + j) * 12 + k * 4);
    const float4 av = *(const float4*)(A + co0);
    const float4 cv = *(const float4*)(C + co0);

    // lane l covers row (l>=32) of each pair, cins (l%32)*4..+3
    const float* xb0 = x + (size_t)b * T * CIN;
    const int l4 = l * 4;
    // load the row-pair starting at batch-local row r (clamped to valid range;
    // clamped loads are prefetch-overrun, data discarded)
    auto loadpair = [&](int r) -> float4 {
        r = (r > T - 2) ? (T - 2) : r;
        return *(const float4*)(xb0 + (size_t)r * CIN + l4);
    };

    // prologue: pairs 0,1,2 (rows t0 .. t0+5)
    float4 v0 = loadpair(t0);
    float4 v1 = loadpair(t0 + 2);
    float4 v2 = loadpair(t0 + 4);
    uint64_t p0 = __ballot(v0.x >= 0.0f);
    uint64_t p1 = __ballot(v0.y >= 0.0f);
    uint64_t p2 = __ballot(v0.z >= 0.0f);
    uint64_t p3 = __ballot(v0.w >= 0.0f);

    float* orow = out + ((size_t)b * TOUT + t0) * COUT + co0;

    #pragma unroll 2
    for (int i = 0; i < TW / 4; ++i) {   // 8 bodies, 4 outputs each
        // prefetch pairs 2i+3, 2i+4 (consumed next body)
        float4 vn1 = loadpair(t0 + 4 * i + 6);
        float4 vn2 = loadpair(t0 + 4 * i + 8);

        uint64_t m0 = __ballot(v1.x >= 0.0f);   // pair 2i+1: rows 4i+2, 4i+3
        uint64_t m1 = __ballot(v1.y >= 0.0f);
        uint64_t m2 = __ballot(v1.z >= 0.0f);
        uint64_t m3 = __ballot(v1.w >= 0.0f);
        uint64_t n0 = __ballot(v2.x >= 0.0f);   // pair 2i+2: rows 4i+4, 4i+5
        uint64_t n1 = __ballot(v2.y >= 0.0f);
        uint64_t n2 = __ballot(v2.z >= 0.0f);
        uint64_t n3 = __ballot(v2.w >= 0.0f);

        // rows 4i..4i+5 as 4-word groups
        uint4 q0 = make_uint4((uint32_t)p0, (uint32_t)p1, (uint32_t)p2, (uint32_t)p3);
        uint4 q1 = make_uint4((uint32_t)(p0 >> 32), (uint32_t)(p1 >> 32), (uint32_t)(p2 >> 32), (uint32_t)(p3 >> 32));
        uint4 q2 = make_uint4((uint32_t)m0, (uint32_t)m1, (uint32_t)m2, (uint32_t)m3);
        uint4 q3 = make_uint4((uint32_t)(m0 >> 32), (uint32_t)(m1 >> 32), (uint32_t)(m2 >> 32), (uint32_t)(m3 >> 32));
        uint4 q4 = make_uint4((uint32_t)n0, (uint32_t)n1, (uint32_t)n2, (uint32_t)n3);
        uint4 q5 = make_uint4((uint32_t)(n0 >> 32), (uint32_t)(n1 >> 32), (uint32_t)(n2 >> 32), (uint32_t)(n3 >> 32));

        f32x4 o0, o1, o2, o3;
        #pragma unroll
        for (int j = 0; j < 4; ++j) {
            int s0 = popc4(q0, kj[j][0]) + popc4(q1, kj[j][1]) + popc4(q2, kj[j][2]);
            int s1 = popc4(q1, kj[j][0]) + popc4(q2, kj[j][1]) + popc4(q3, kj[j][2]);
            int s2 = popc4(q2, kj[j][0]) + popc4(q3, kj[j][1]) + popc4(q4, kj[j][2]);
            int s3 = popc4(q3, kj[j][0]) + popc4(q4, kj[j][1]) + popc4(q5, kj[j][2]);
            float aj = (&av.x)[j], cj = (&cv.x)[j];
            o0[j] = fmaf((float)s0, aj, cj);
            o1[j] = fmaf((float)s1, aj, cj);
            o2[j] = fmaf((float)s2, aj, cj);
            o3[j] = fmaf((float)s3, aj, cj);
        }

        float* op = orow + (size_t)(4 * i) * COUT;
        __builtin_nontemporal_store(o0, (f32x4*)op);
        __builtin_nontemporal_store(o1, (f32x4*)(op + COUT));
        __builtin_nontemporal_store(o2, (f32x4*)(op + 2 * COUT));
        __builtin_nontemporal_store(o3, (f32x4*)(op + 3 * COUT));

        // slide: masks <- pair 2i+2; data <- pairs 2i+3, 2i+4
        p0 = n0; p1 = n1; p2 = n2; p3 = n3;
        v1 = vn1; v2 = vn2;
    }
}

extern "C" void kernel_launch(void* const* d_in, const int* in_sizes, int n_in,
                              void* d_out, int out_size, void* d_ws, size_t ws_size,
                              hipStream_t stream) {
    const float* x    = (const float*)d_in[0];
    const float* ker  = (const float*)d_in[1];
    const float* bias = (const float*)d_in[2];
    const float* beta = (const float*)d_in[3];
    const float* mean = (const float*)d_in[4];
    const float* var  = (const float*)d_in[5];
    float* out = (float*)d_out;

    // workspace: kbT (12 KB) | A (1 KB) | C (1 KB)
    uint32_t* kbT = (uint32_t*)d_ws;
    float*    A   = (float*)(kbT + (size_t)COUT * 12);
    float*    C   = A + COUT;

    pack_w_kernel<<<KW * 4, 256, 0, stream>>>(ker, bias, beta, mean, var, kbT, A, C);
    conv_kernel<<<(B * NWIN) / WPB, 256, 0, stream>>>(x, kbT, A, C, out);
}